// Round 10
// baseline (171.578 us; speedup 1.0000x reference)
//
#include <hip/hip_runtime.h>
#include <stdint.h>

// B=8, S=2048, F=512, D=128, C=1000. I/O fp32; internal bf16 MFMA, fp32 accum.
// R10 = R9 flash restructure with the V^T epilogue copy bug fixed (R9 copied
// only half of each 64-short segment -> half of vt was poison -> absmax 4.2e-2,
// half of R3's missing-attention signature 8.2e-2).
// 4 kernels: prep, qkv_proj, flash_attn, final_proj.
// Fixed exp offset (-10) => no running max => numerator and l are plain sums
// => single KV sweep per q-row computes BOTH l and num = sum_k e*V.
// Swapped QK^T (mfma(K,Q)) puts q on lane&15 -> P^T feeds PV B-operand via
// 8 shfl per chunk; V stored TRANSPOSED (vt[b][d][s], produced by qkv's V
// epilogue via an LDS tile transpose) -> PV A-frags are contiguous bf16x8.
// exp = single v_exp_f32 (Q pre-scaled by log2e in qkv epilogue, R5-validated).
#define NB 8
#define SS 2048
#define FF 512
#define DD 128
#define CC 1000

typedef __attribute__((ext_vector_type(8))) short bf16x8;
typedef __attribute__((ext_vector_type(4))) float f32x4;
typedef __attribute__((ext_vector_type(4))) unsigned int u32x4;
typedef __attribute__((ext_vector_type(2))) unsigned int u32x2;

__device__ __forceinline__ short f2bf(float f) {
    uint32_t u;
    __builtin_memcpy(&u, &f, 4);
    u = (u + 0x7fffu + ((u >> 16) & 1u)) >> 16;   // RNE
    return (short)u;
}
__device__ __forceinline__ float bf2f(short h) {
    uint32_t u = ((uint32_t)(uint16_t)h) << 16;
    float f;
    __builtin_memcpy(&f, &u, 4);
    return f;
}
// 2x f32 -> packed bf16x2 (lo=a, hi=b), single HW instr (RNE)
__device__ __forceinline__ uint32_t cvtpk(float a, float b) {
    uint32_t r;
    asm("v_cvt_pk_bf16_f32 %0, %1, %2" : "=v"(r) : "v"(a), "v"(b));
    return r;
}
// 2^x via v_exp_f32
__device__ __forceinline__ float exp2_hw(float x) {
    float r;
    asm("v_exp_f32 %0, %1" : "=v"(r) : "v"(x));
    return r;
}
// async 16B global->LDS; LDS dest = wave-uniform base + lane*16
__device__ __forceinline__ void async16(const void* g, void* l) {
    __builtin_amdgcn_global_load_lds(
        (const __attribute__((address_space(1))) uint32_t*)g,
        (__attribute__((address_space(3))) uint32_t*)l, 16, 0, 0);
}

// ---------------------------------------------------------------------------
// Kernel 0 (prep): transpose+cast W [F][D]f32 -> [D][F]bf16; block 0 also
// zero-inits accum (written by flash_attn atomics). grid = 768 blocks.
// ---------------------------------------------------------------------------
__global__ void prep(const float* __restrict__ Wq, const float* __restrict__ Wk,
                     const float* __restrict__ Wv, short* __restrict__ Wt,
                     float* __restrict__ accum)
{
    if (blockIdx.x == 0) {
        int t = threadIdx.x;
        accum[t] = 0.f; accum[256 + t] = 0.f;
        accum[512 + t] = 0.f; accum[768 + t] = 0.f;
    }
    int id = blockIdx.x * 256 + threadIdx.x;      // 0..196607
    int w = id >> 16, rem = id & 65535;
    int n = rem >> 9, kx = rem & 511;
    const float* Wsrc = (w == 0) ? Wq : (w == 1) ? Wk : Wv;
    Wt[w * 65536 + n * 512 + kx] = f2bf(Wsrc[kx * 128 + n]);
}

// ---------------------------------------------------------------------------
// Kernel 1: fused QKV projection (x fp32 read directly, reg-staged cvt_pk
// into swizzled LDS; Wt via async16; T14 split; dbuf).
// mat==0 (Q): output pre-scaled by log2(e)  [flash uses exp2].
// mat==1 (K): row-major ko[b][s][d].
// mat==2 (V): LDS tile-transpose -> vt[b][d][s] (PV A-operand layout).
// ---------------------------------------------------------------------------
__global__ __launch_bounds__(256) void qkv_proj(
    const float* __restrict__ x, const short* __restrict__ Wt,
    const float* __restrict__ bq, const float* __restrict__ bk, const float* __restrict__ bv,
    short* __restrict__ qo, short* __restrict__ ko, short* __restrict__ vt)
{
    __shared__ __align__(16) short SMEM[32768];       // 64 KB: As | Bs, reused as T
    short* As = SMEM;                                  // [2][128*64]
    short* Bs = SMEM + 16384;                          // [2][128*64]

    const int m0   = blockIdx.x * 128;
    const int mat  = blockIdx.y;
    const int tid  = threadIdx.x;
    const int wave = tid >> 6, lane = tid & 63;
    const int quad = lane >> 4, l16 = lane & 15;
    const int wr = wave >> 1, wc = wave & 1;

    const short* Wm = Wt + mat * 65536;

    f32x4 acc[4][4];
    for (int i = 0; i < 4; i++)
        for (int j = 0; j < 4; j++) acc[i][j] = (f32x4){0.f, 0.f, 0.f, 0.f};

    const int sr = lane >> 3;
    const int sc = (lane & 7) ^ (sr & 7);

    float4 a0[4], a1[4];                              // in-flight A tile

#define A_LOAD(kk)                                                          \
    for (int i = 0; i < 4; i++) {                                           \
        int ins = wave * 4 + i;                                             \
        int r = ins * 8 + sr;                                               \
        const float4* s4 = (const float4*)(x + (size_t)(m0 + r) * 512 + (kk) + sc * 8); \
        a0[i] = s4[0]; a1[i] = s4[1];                                       \
    }
#define A_WRITE(buf)                                                        \
    for (int i = 0; i < 4; i++) {                                           \
        int ins = wave * 4 + i;                                             \
        u32x4 p;                                                            \
        p[0] = cvtpk(a0[i].x, a0[i].y);                                     \
        p[1] = cvtpk(a0[i].z, a0[i].w);                                     \
        p[2] = cvtpk(a1[i].x, a1[i].y);                                     \
        p[3] = cvtpk(a1[i].z, a1[i].w);                                     \
        *(u32x4*)&As[(buf) * 8192 + ins * 512 + lane * 8] = p;              \
    }
#define B_STAGE(buf, kk)                                                    \
    for (int i = 0; i < 4; i++) {                                           \
        int ins = wave * 4 + i;                                             \
        int r = ins * 8 + sr;                                               \
        async16(Wm + r * 512 + (kk) + sc * 8, &Bs[(buf) * 8192 + ins * 512]); \
    }

    A_LOAD(0)
    B_STAGE(0, 0)
    A_WRITE(0)
    __syncthreads();

    int cur = 0;
    for (int t = 0; t < 8; t++) {
        if (t < 7) {
            A_LOAD((t + 1) * 64)
            B_STAGE(cur ^ 1, (t + 1) * 64)
        }
        for (int kc = 0; kc < 2; kc++) {
            bf16x8 af[4], bfr[4];
            for (int mt = 0; mt < 4; mt++) {
                int R = wr * 64 + mt * 16 + l16, cc = kc * 4 + quad;
                af[mt] = *(const bf16x8*)&As[cur * 8192 + (R * 8 + (cc ^ (R & 7))) * 8];
            }
            for (int nt = 0; nt < 4; nt++) {
                int R = wc * 64 + nt * 16 + l16, cc = kc * 4 + quad;
                bfr[nt] = *(const bf16x8*)&Bs[cur * 8192 + (R * 8 + (cc ^ (R & 7))) * 8];
            }
            for (int mt = 0; mt < 4; mt++)
                for (int nt = 0; nt < 4; nt++)
                    acc[mt][nt] = __builtin_amdgcn_mfma_f32_16x16x32_bf16(
                        af[mt], bfr[nt], acc[mt][nt], 0, 0, 0);
        }
        if (t < 7) { A_WRITE(cur ^ 1) }
        __syncthreads();
        cur ^= 1;
    }
#undef A_LOAD
#undef A_WRITE
#undef B_STAGE

    if (mat != 2) {
        const float* bias = (mat == 0) ? bq : bk;
        short* outp = (mat == 0) ? qo : ko;
        const float scale = (mat == 0) ? 1.44269504f : 1.0f;  // log2(e) into Q
        for (int mt = 0; mt < 4; mt++) {
            int grow_base = m0 + wr * 64 + mt * 16 + quad * 4;
            for (int nt = 0; nt < 4; nt++) {
                int col = wc * 64 + nt * 16 + l16;
                float bb = bias[col];
                for (int r = 0; r < 4; r++)
                    outp[(grow_base + r) * 128 + col] = f2bf((acc[mt][nt][r] + bb) * scale);
            }
        }
    } else {
        // V^T epilogue: T[col=d][row=s_local], row-stride 136 shorts
        // (136 -> every 8-short segment read is 16B-aligned: 272d+16j % 16 == 0)
        short* T = SMEM;                               // 128*136 shorts = 34 KB
        for (int mt = 0; mt < 4; mt++) {
            int rowb = wr * 64 + mt * 16 + quad * 4;
            for (int nt = 0; nt < 4; nt++) {
                int colb = wc * 64 + nt * 16 + l16;
                float bb = bv[colb];
                *(uint32_t*)&T[colb * 136 + rowb]     = cvtpk(acc[mt][nt][0] + bb, acc[mt][nt][1] + bb);
                *(uint32_t*)&T[colb * 136 + rowb + 2] = cvtpk(acc[mt][nt][2] + bb, acc[mt][nt][3] + bb);
            }
        }
        __syncthreads();
        int d = tid >> 1, half = tid & 1;
        int bb2 = m0 >> 11, s0 = m0 & 2047;
        short* dst = vt + ((size_t)bb2 * 128 + d) * 2048 + s0 + half * 64;
        for (int j = 0; j < 8; j++) {                  // 8 x 8 shorts = full 64
            u32x4 o = *(const u32x4*)&T[d * 136 + half * 64 + j * 8];
            *(u32x4*)(dst + j * 8) = o;
        }
    }
}

// ---------------------------------------------------------------------------
// Kernel 2 (flash_attn): one block per (qt of 64 q-rows, b). 4 waves x 16 q.
// Single KV sweep, tiles of 64: stage K (swizzled) + V^T (swizzled), dbuf.
// S^T = mfma(K,Q) [q = lane&15]; e = exp2(S'-10*log2e); lsum += e;
// P^T packed bf16 -> PV B-frag via 8 shfl/chunk; num^T[d][q] += V^T x P^T.
// End: l = 2-shfl reduce; o = num/l; sum over q via 4-shfl; atomicAdd accum.
// grid (32, 8) = 256 blocks.
// ---------------------------------------------------------------------------
__global__ __launch_bounds__(256) void flash_attn(
    const short* __restrict__ q, const short* __restrict__ k,
    const short* __restrict__ vt, float* __restrict__ accum)
{
    __shared__ __align__(16) short ks[2][64 * 128];   // K tiles, swizzled C=16
    __shared__ __align__(16) short vs[2][128 * 64];   // V^T tiles, swizzled C=8

    const int b  = blockIdx.y;
    const int q0 = blockIdx.x * 64;
    const int tid  = threadIdx.x;
    const int wave = tid >> 6, lane = tid & 63;
    const int quad = lane >> 4, l16 = lane & 15;

    // Q as B-frag: col=l16=q, k=d chunks (contiguous row reads). Q pre-scaled.
    bf16x8 qf[4];
#pragma unroll
    for (int c = 0; c < 4; c++)
        qf[c] = *(const bf16x8*)(q + (size_t)(b * 2048 + q0 + wave * 16 + l16) * 128
                                   + c * 32 + quad * 8);

    f32x4 num[8];
#pragma unroll
    for (int i = 0; i < 8; i++) num[i] = (f32x4){0.f, 0.f, 0.f, 0.f};
    float lsum = 0.f;

    const int krl = lane >> 4;                        // 0..3
    const int vrl = lane >> 3;                        // 0..7

#define KV_STAGE(buf, t)                                                      \
    for (int i = 0; i < 4; i++) {                                             \
        int g = wave * 4 + i;                                                 \
        int kr = g * 4 + krl;                                                 \
        int kc8 = (lane & 15) ^ (kr & 15);                                    \
        async16(k + (size_t)(b * 2048 + (t) * 64 + kr) * 128 + kc8 * 8,       \
                &ks[buf][g * 512]);                                           \
        int vr = g * 8 + vrl;                                                 \
        int vc = (lane & 7) ^ vrl;                                            \
        async16(vt + ((size_t)b * 128 + vr) * 2048 + (t) * 64 + vc * 8,       \
                &vs[buf][g * 512]);                                           \
    }

    KV_STAGE(0, 0)
    __syncthreads();

    for (int t = 0; t < 32; t++) {
        if (t < 31) { KV_STAGE((t + 1) & 1, t + 1) }

        // ---- swapped QK^T: S^T[kv][q], kv-tile ct: row=quad*4+reg, col=l16=q
        f32x4 Sf[4];
        uint32_t pk[4][2];
        __builtin_amdgcn_s_setprio(1);
#pragma unroll
        for (int ct = 0; ct < 4; ct++) {
            Sf[ct] = (f32x4){0.f, 0.f, 0.f, 0.f};
            int R = ct * 16 + l16;
#pragma unroll
            for (int c = 0; c < 4; c++) {
                int cc = c * 4 + quad;
                bf16x8 kb = *(const bf16x8*)&ks[t & 1][(R * 16 + (cc ^ l16)) * 8];
                Sf[ct] = __builtin_amdgcn_mfma_f32_16x16x32_bf16(
                    kb, qf[c], Sf[ct], 0, 0, 0);      // A=K, B=Q -> S^T
            }
        }
        __builtin_amdgcn_s_setprio(0);

        // ---- e = exp(S-10) = 2^(S*log2e - 10*log2e); pack reg-pairs (kv pairs)
#pragma unroll
        for (int ct = 0; ct < 4; ct++) {
            float e0 = exp2_hw(Sf[ct][0] - 14.4269504f);
            float e1 = exp2_hw(Sf[ct][1] - 14.4269504f);
            float e2 = exp2_hw(Sf[ct][2] - 14.4269504f);
            float e3 = exp2_hw(Sf[ct][3] - 14.4269504f);
            lsum += (e0 + e1) + (e2 + e3);
            pk[ct][0] = cvtpk(e0, e1);
            pk[ct][1] = cvtpk(e2, e3);
        }

        // ---- PV: num^T[d][q] += V^T[d][kv] * P^T[kv][q], K=64 as 2 chunks
#pragma unroll
        for (int ch = 0; ch < 2; ch++) {
            // B-frag: lane (quad,l16) needs P^T[kv=ch*32+quad*8+j][q=l16]
            int srcA = l16 + 32 * (quad & 1);         // source quad 2*(quad&1)
            int srcB = srcA + 16;                     // source quad 2*(quad&1)+1
            uint32_t a0 = __shfl((int)pk[ch * 2][0], srcA);
            uint32_t b0 = __shfl((int)pk[ch * 2 + 1][0], srcA);
            uint32_t a1 = __shfl((int)pk[ch * 2][1], srcA);
            uint32_t b1 = __shfl((int)pk[ch * 2 + 1][1], srcA);
            uint32_t a2 = __shfl((int)pk[ch * 2][0], srcB);
            uint32_t b2 = __shfl((int)pk[ch * 2 + 1][0], srcB);
            uint32_t a3 = __shfl((int)pk[ch * 2][1], srcB);
            uint32_t b3 = __shfl((int)pk[ch * 2 + 1][1], srcB);
            u32x4 pbu;                                // ct = ch*2 + (quad>>1)
            pbu[0] = (quad >> 1) ? b0 : a0;
            pbu[1] = (quad >> 1) ? b1 : a1;
            pbu[2] = (quad >> 1) ? b2 : a2;
            pbu[3] = (quad >> 1) ? b3 : a3;
            bf16x8 pb;
            __builtin_memcpy(&pb, &pbu, 16);
            __builtin_amdgcn_s_setprio(1);
#pragma unroll
            for (int dt = 0; dt < 8; dt++) {
                int row = dt * 16 + l16;
                bf16x8 va = *(const bf16x8*)&vs[t & 1][(row * 8 + ((ch * 4 + quad) ^ (row & 7))) * 8];
                num[dt] = __builtin_amdgcn_mfma_f32_16x16x32_bf16(
                    va, pb, num[dt], 0, 0, 0);        // A=V^T, B=P^T
            }
            __builtin_amdgcn_s_setprio(0);
        }
        __syncthreads();
    }
#undef KV_STAGE

    // ---- l reduce (sum over quads), normalize, sum over q, accumulate
    lsum += __shfl_xor(lsum, 16);
    lsum += __shfl_xor(lsum, 32);
    float linv = 1.0f / lsum;                         // l for q = l16

#pragma unroll
    for (int dt = 0; dt < 8; dt++)
#pragma unroll
        for (int r = 0; r < 4; r++) {
            float v = num[dt][r] * linv;
            v += __shfl_xor(v, 1);
            v += __shfl_xor(v, 2);
            v += __shfl_xor(v, 4);
            v += __shfl_xor(v, 8);
            if (l16 == 0)
                atomicAdd(&accum[b * 128 + dt * 16 + quad * 4 + r], v);
        }
}

// ---------------------------------------------------------------------------
// Kernel 3: out[b][c] = (accum[b][:]/2048) . Wl[:,c] + bl[c], fp32 out.
// 32 blocks spread the 4MB Wl read (R6 lesson: never 1 block).
// ---------------------------------------------------------------------------
__global__ void final_proj(const float* __restrict__ accum, const float* __restrict__ Wl,
                           const float* __restrict__ bl, float* __restrict__ out)
{
    int id = blockIdx.x * 256 + threadIdx.x;
    if (id >= NB * CC) return;
    int b = id / CC, c = id % CC;
    float s = 0.f;
    for (int d = 0; d < 128; d++)
        s += accum[b * 128 + d] * Wl[d * 1000 + c];
    out[id] = s * (1.0f / 2048.0f) + bl[c];
}

// ---------------------------------------------------------------------------
extern "C" void kernel_launch(void* const* d_in, const int* in_sizes, int n_in,
                              void* d_out, int out_size, void* d_ws, size_t ws_size,
                              hipStream_t stream) {
    const float* x  = (const float*)d_in[0];
    const float* Wq = (const float*)d_in[1];
    const float* bq = (const float*)d_in[2];
    const float* Wk = (const float*)d_in[3];
    const float* bk = (const float*)d_in[4];
    const float* Wv = (const float*)d_in[5];
    const float* bv = (const float*)d_in[6];
    const float* Wl = (const float*)d_in[7];
    const float* bl = (const float*)d_in[8];
    float* out = (float*)d_out;

    char* ws = (char*)d_ws;
    short* qo  = (short*)(ws);                    // 4 MiB (Q, pre-scaled log2e)
    short* ko  = (short*)(ws + 4194304);          // 4 MiB (K row-major)
    short* vt  = (short*)(ws + 8388608);          // 4 MiB (V TRANSPOSED [b][d][s])
    short* Wt  = (short*)(ws + 12582912);         // 384 KiB
    float* acc = (float*)(ws + 12976128);         // 4 KiB
    // total ~12.4 MiB of d_ws

    prep<<<768, 256, 0, stream>>>(Wq, Wk, Wv, Wt, acc);
    qkv_proj<<<dim3(128, 3), 256, 0, stream>>>(x, Wt, bq, bk, bv, qo, ko, vt);
    flash_attn<<<dim3(32, 8), 256, 0, stream>>>(qo, ko, vt, acc);
    final_proj<<<(NB * CC + 255) / 256, 256, 0, stream>>>(acc, Wl, bl, out);
}

// Round 12
// 143.880 us; speedup vs baseline: 1.1925x; 1.1925x over previous
//
#include <hip/hip_runtime.h>
#include <stdint.h>

// B=8, S=2048, F=512, D=128, C=1000. I/O fp32; internal bf16 MFMA, fp32 accum.
// mean-attention: w[k] = sum_s exp(S[s,k]-10)/l[s]; out_sum = w.V row-major.
// R10 post-mortem: flash regressed (68us, 1 blk/CU, serial chain); algebra
// showed qkv_proj ~75-85us dominates (reads x fp32 3x = 190MB).
// R11: qkv_mega = ONE GEMM C[16384x384] = x[16384x512] @ Wt^T (x read ONCE).
// BM=64 BN=384 BK=64, 512 thr (8 waves x 3 n-frags x 4 m-frags), grid 256,
// LDS 112KB dbuf, same swizzled-chunk staging as verified R8. Epilogue
// scatters cols to qo/ko/vo row-major. Attention = R8 kernels verbatim.
// (R12 resubmit: R11 never ran — container infrastructure failure.)
#define NB 8
#define SS 2048
#define FF 512
#define DD 128
#define CC 1000
#define KC 8              // KV split factor
#define CHUNK (SS / KC)   // 256

typedef __attribute__((ext_vector_type(8))) short bf16x8;
typedef __attribute__((ext_vector_type(4))) float f32x4;
typedef __attribute__((ext_vector_type(4))) unsigned int u32x4;

__device__ __forceinline__ short f2bf(float f) {
    uint32_t u;
    __builtin_memcpy(&u, &f, 4);
    u = (u + 0x7fffu + ((u >> 16) & 1u)) >> 16;   // RNE
    return (short)u;
}
__device__ __forceinline__ float bf2f(short h) {
    uint32_t u = ((uint32_t)(uint16_t)h) << 16;
    float f;
    __builtin_memcpy(&f, &u, 4);
    return f;
}
// 2x f32 -> packed bf16x2 (lo=a, hi=b), single HW instr (RNE)
__device__ __forceinline__ uint32_t cvtpk(float a, float b) {
    uint32_t r;
    asm("v_cvt_pk_bf16_f32 %0, %1, %2" : "=v"(r) : "v"(a), "v"(b));
    return r;
}
// async 16B global->LDS; LDS dest = wave-uniform base + lane*16
__device__ __forceinline__ void async16(const void* g, void* l) {
    __builtin_amdgcn_global_load_lds(
        (const __attribute__((address_space(1))) uint32_t*)g,
        (__attribute__((address_space(3))) uint32_t*)l, 16, 0, 0);
}

// ---------------------------------------------------------------------------
// Kernel 0 (prep): transpose+cast W [F][D]f32 x3 -> Wt[384][512] bf16
// (row = global output col: mat*128 + d). grid = 768 blocks.
// ---------------------------------------------------------------------------
__global__ void prep(const float* __restrict__ Wq, const float* __restrict__ Wk,
                     const float* __restrict__ Wv, short* __restrict__ Wt)
{
    int id = blockIdx.x * 256 + threadIdx.x;      // 0..196607
    int w = id >> 16, rem = id & 65535;
    int n = rem >> 9, kx = rem & 511;
    const float* Wsrc = (w == 0) ? Wq : (w == 1) ? Wk : Wv;
    Wt[w * 65536 + n * 512 + kx] = f2bf(Wsrc[kx * 128 + n]);
}

// ---------------------------------------------------------------------------
// Kernel 1 (qkv_mega): C[16384x384] = bf16(x) @ Wt^T + bias, x read ONCE.
// 512 threads. Wave w owns output cols [48w, 48w+48) (3 n-frags); 4 m-frags
// cover the 64-row m-tile. A reg-staged (fp32->cvtpk->swizzled LDS), B via
// async16 (same chunk swizzle: chunk (r,c) at r*8 + (c ^ (r&7))). T14 split +
// double buffer. Epilogue: col>>7 selects qo/ko/vo (+bias), row-major.
// ---------------------------------------------------------------------------
__global__ __launch_bounds__(512) void qkv_mega(
    const float* __restrict__ x, const short* __restrict__ Wt,
    const float* __restrict__ bq, const float* __restrict__ bk, const float* __restrict__ bv,
    short* __restrict__ qo, short* __restrict__ ko, short* __restrict__ vo)
{
    __shared__ __align__(16) short As[2][64 * 64];    // 16 KB
    __shared__ __align__(16) short Bs[2][384 * 64];   // 96 KB

    const int m0   = blockIdx.x * 64;
    const int tid  = threadIdx.x;
    const int wave = tid >> 6, lane = tid & 63;
    const int quad = lane >> 4, l16 = lane & 15;

    f32x4 acc[4][3];
    for (int i = 0; i < 4; i++)
        for (int j = 0; j < 3; j++) acc[i][j] = (f32x4){0.f, 0.f, 0.f, 0.f};

    const int sr  = lane >> 3;                    // 0..7
    const int sc  = (lane & 7) ^ (sr & 7);
    const int ar  = tid >> 3;                     // 0..63  (A row)
    const int ac8 = tid & 7;                      // A source chunk col
    const int aslot = ar * 8 + (ac8 ^ (ar & 7));  // swizzled A chunk slot

    float4 a0, a1;                                // in-flight A (8 fp32/lane)

#define A_LOAD(kk) {                                                        \
        const float4* s4 = (const float4*)(x + (size_t)(m0 + ar) * 512 + (kk) + ac8 * 8); \
        a0 = s4[0]; a1 = s4[1]; }
#define A_WRITE(buf) {                                                      \
        u32x4 p;                                                            \
        p[0] = cvtpk(a0.x, a0.y); p[1] = cvtpk(a0.z, a0.w);                 \
        p[2] = cvtpk(a1.x, a1.y); p[3] = cvtpk(a1.z, a1.w);                 \
        *(u32x4*)&As[buf][aslot * 8] = p; }
#define B_STAGE(buf, kk)                                                    \
    for (int i = 0; i < 6; i++) {                                           \
        int ins = wave * 6 + i;                   /* 0..47 */               \
        int r = ins * 8 + sr;                     /* 0..383 */              \
        async16(Wt + r * 512 + (kk) + sc * 8, &Bs[buf][ins * 512]);         \
    }

    A_LOAD(0)
    B_STAGE(0, 0)
    A_WRITE(0)
    __syncthreads();                              // lgkm + vmcnt drained

    int cur = 0;
    for (int t = 0; t < 8; t++) {
        if (t < 7) {
            A_LOAD((t + 1) * 64)                  // issue early (T14)
            B_STAGE(cur ^ 1, (t + 1) * 64)
        }

        for (int kc = 0; kc < 2; kc++) {
            bf16x8 af[4], bfr[3];
            int cc = kc * 4 + quad;
            for (int mt = 0; mt < 4; mt++) {
                int R = mt * 16 + l16;            // 0..63
                af[mt] = *(const bf16x8*)&As[cur][(R * 8 + (cc ^ (R & 7))) * 8];
            }
            for (int nf = 0; nf < 3; nf++) {
                int R = wave * 48 + nf * 16 + l16; // 0..383 (output col)
                bfr[nf] = *(const bf16x8*)&Bs[cur][(R * 8 + (cc ^ (R & 7))) * 8];
            }
            for (int mt = 0; mt < 4; mt++)
                for (int nf = 0; nf < 3; nf++)
                    acc[mt][nf] = __builtin_amdgcn_mfma_f32_16x16x32_bf16(
                        af[mt], bfr[nf], acc[mt][nf], 0, 0, 0);
        }
        if (t < 7) { A_WRITE(cur ^ 1) }           // A landed under MFMA
        __syncthreads();
        cur ^= 1;
    }
#undef A_LOAD
#undef A_WRITE
#undef B_STAGE

    const float* const bps[3] = { bq, bk, bv };
    short* const ops[3] = { qo, ko, vo };
    for (int nf = 0; nf < 3; nf++) {
        int colb = wave * 48 + nf * 16;           // frag never straddles mats
        int mat = colb >> 7;
        int lc  = (colb & 127) + l16;
        float bb = bps[mat][lc];
        short* outp = ops[mat];
        for (int mt = 0; mt < 4; mt++) {
            int grow = m0 + mt * 16 + quad * 4;   // C/D row = quad*4+reg
            for (int r = 0; r < 4; r++)
                outp[(size_t)(grow + r) * 128 + lc] = f2bf(acc[mt][nf][r] + bb);
        }
    }
}

// ---------------------------------------------------------------------------
// Kernel 2 (pass 1): l_part[kc][b][row] = per-chunk row sums of exp(S-10).
// 128 q-rows/block, KV tile 64, double-buffered K + setprio. Block (0,0,0)
// zero-inits accum. grid = (16, 8, KC).  [R8 verbatim]
// ---------------------------------------------------------------------------
__global__ __launch_bounds__(256) void attn_l(
    const short* __restrict__ q, const short* __restrict__ k,
    float* __restrict__ l_part, float* __restrict__ accum)
{
    __shared__ __align__(16) short ks[2][64 * 128];   // swizzled, C=16

    const int b  = blockIdx.y;
    const int q0 = blockIdx.x * 128;
    const int lq = blockIdx.z;
    const int c0 = lq * CHUNK;
    const int tid  = threadIdx.x;
    const int wave = tid >> 6, lane = tid & 63;
    const int quad = lane >> 4, l16 = lane & 15;

    if (blockIdx.x == 0 && blockIdx.y == 0 && blockIdx.z == 0) {
        accum[tid] = 0.f; accum[256 + tid] = 0.f;
        accum[512 + tid] = 0.f; accum[768 + tid] = 0.f;
    }

    bf16x8 qf[2][4];
    for (int m = 0; m < 2; m++)
        for (int c = 0; c < 4; c++)
            qf[m][c] = *(const bf16x8*)(q + (b * 2048 + q0 + wave * 32 + m * 16 + l16) * 128
                                          + c * 32 + quad * 8);

    float lsum[2][4] = {{0.f,0.f,0.f,0.f},{0.f,0.f,0.f,0.f}};
    const int krl = lane >> 4;                        // 0..3

#define K_STAGE(buf, s0)                                                     \
    for (int i = 0; i < 4; i++) {                                            \
        int ik = wave * 4 + i;                                               \
        int kr = ik * 4 + krl;                                               \
        int kc8 = (lane & 15) ^ (kr & 15);                                   \
        async16(k + (b * 2048 + (s0) + kr) * 128 + kc8 * 8, &ks[buf][ik * 512]); \
    }

    K_STAGE(0, c0)
    __syncthreads();

    int cur = 0;
    for (int t = 0; t < CHUNK / 64; t++) {
        if (t < CHUNK / 64 - 1) { K_STAGE(cur ^ 1, c0 + (t + 1) * 64) }

        for (int ct = 0; ct < 4; ct++) {
            f32x4 Sf[2];
            Sf[0] = (f32x4){0.f,0.f,0.f,0.f};
            Sf[1] = (f32x4){0.f,0.f,0.f,0.f};
            int R = ct * 16 + l16;                    // R&15 == l16
            __builtin_amdgcn_s_setprio(1);
            for (int c = 0; c < 4; c++) {
                int cc = c * 4 + quad;
                bf16x8 kb = *(const bf16x8*)&ks[cur][(R * 16 + (cc ^ l16)) * 8];
                for (int m = 0; m < 2; m++)
                    Sf[m] = __builtin_amdgcn_mfma_f32_16x16x32_bf16(
                        qf[m][c], kb, Sf[m], 0, 0, 0);
            }
            __builtin_amdgcn_s_setprio(0);
            for (int m = 0; m < 2; m++)
                for (int r = 0; r < 4; r++)
                    lsum[m][r] += __expf(Sf[m][r] - 10.0f);
        }
        __syncthreads();
        cur ^= 1;
    }

    for (int m = 0; m < 2; m++)
        for (int r = 0; r < 4; r++) {
            float lv = lsum[m][r];
            lv += __shfl_xor(lv, 1);
            lv += __shfl_xor(lv, 2);
            lv += __shfl_xor(lv, 4);
            lv += __shfl_xor(lv, 8);
            if (l16 == 0)
                l_part[(lq * 8 + b) * 2048 + q0 + wave * 32 + m * 16 + quad * 4 + r] = lv;
        }
}

// ---------------------------------------------------------------------------
// Kernel 3 (pass 2): w_part[qt][b][k] = sum over this block's 128 q-rows of
// exp(S-10)/l_total[row]. Plain stores -> no atomics. grid = (16, 8, KC).
// [R8 verbatim]
// ---------------------------------------------------------------------------
__global__ __launch_bounds__(256) void attn_w(
    const short* __restrict__ q, const short* __restrict__ k,
    const float* __restrict__ l_part, float* __restrict__ w_part)
{
    __shared__ __align__(16) short ks[2][64 * 128];   // swizzled, C=16
    __shared__ float wl[4][256];

    const int b  = blockIdx.y;
    const int qt = blockIdx.x;
    const int q0 = qt * 128;
    const int lq = blockIdx.z;
    const int c0 = lq * CHUNK;
    const int tid  = threadIdx.x;
    const int wave = tid >> 6, lane = tid & 63;
    const int quad = lane >> 4, l16 = lane & 15;

    bf16x8 qf[2][4];
    for (int m = 0; m < 2; m++)
        for (int c = 0; c < 4; c++)
            qf[m][c] = *(const bf16x8*)(q + (b * 2048 + q0 + wave * 32 + m * 16 + l16) * 128
                                          + c * 32 + quad * 8);

    float linv[2][4];
    for (int m = 0; m < 2; m++)
        for (int r = 0; r < 4; r++) {
            int row = q0 + wave * 32 + m * 16 + quad * 4 + r;
            float lt = 0.f;
            for (int kc = 0; kc < KC; kc++) lt += l_part[(kc * 8 + b) * 2048 + row];
            linv[m][r] = 1.0f / lt;
        }

    const int krl = lane >> 4;

    K_STAGE(0, c0)
    __syncthreads();

    int cur = 0;
    for (int t = 0; t < CHUNK / 64; t++) {
        if (t < CHUNK / 64 - 1) { K_STAGE(cur ^ 1, c0 + (t + 1) * 64) }
        int s0 = c0 + t * 64;

        for (int ct = 0; ct < 4; ct++) {
            f32x4 Sf[2];
            Sf[0] = (f32x4){0.f,0.f,0.f,0.f};
            Sf[1] = (f32x4){0.f,0.f,0.f,0.f};
            int R = ct * 16 + l16;
            __builtin_amdgcn_s_setprio(1);
            for (int c = 0; c < 4; c++) {
                int cc = c * 4 + quad;
                bf16x8 kb = *(const bf16x8*)&ks[cur][(R * 16 + (cc ^ l16)) * 8];
                for (int m = 0; m < 2; m++)
                    Sf[m] = __builtin_amdgcn_mfma_f32_16x16x32_bf16(
                        qf[m][c], kb, Sf[m], 0, 0, 0);
            }
            __builtin_amdgcn_s_setprio(0);
            float cs = 0.f;
            for (int m = 0; m < 2; m++)
                for (int r = 0; r < 4; r++)
                    cs += __expf(Sf[m][r] - 10.0f) * linv[m][r];
            cs += __shfl_xor(cs, 16);
            cs += __shfl_xor(cs, 32);
            if (quad == 0) wl[wave][(s0 - c0) + ct * 16 + l16] = cs;
        }
        __syncthreads();
        cur ^= 1;
    }
#undef K_STAGE

    {
        float s = wl[0][tid] + wl[1][tid] + wl[2][tid] + wl[3][tid];
        w_part[(qt * 8 + b) * 2048 + c0 + tid] = s;
    }
}

// ---------------------------------------------------------------------------
// Kernel 4 (wv): accum[b][d] += sum_s w[b][s] * V[b][s][d], V row-major.
// [R8 verbatim]
// ---------------------------------------------------------------------------
__global__ __launch_bounds__(256) void wv(
    const float* __restrict__ w_part, const short* __restrict__ vo,
    float* __restrict__ accum)
{
    __shared__ float wsh[128];
    __shared__ float red[16][129];                 // +1 pad: conflict-free reads
    const int b    = blockIdx.x;
    const int slab = blockIdx.y;                   // 16 slabs of 128 rows
    const int tid  = threadIdx.x;

    if (tid < 128) {
        int s = slab * 128 + tid;
        float wsum = 0.f;
        for (int qt = 0; qt < 16; qt++) wsum += w_part[(qt * 8 + b) * 2048 + s];
        wsh[tid] = wsum;
    }
    __syncthreads();

    const int dgrp = tid & 15, sgrp = tid >> 4;
    const int d0 = dgrp * 8;
    float a[8] = {0.f,0.f,0.f,0.f,0.f,0.f,0.f,0.f};
    for (int i = 0; i < 8; i++) {
        int sl = sgrp * 8 + i;
        bf16x8 v = *(const bf16x8*)(vo + (size_t)(b * 2048 + slab * 128 + sl) * 128 + d0);
        float w = wsh[sl];
        for (int j = 0; j < 8; j++) a[j] += w * bf2f(v[j]);
    }
    for (int j = 0; j < 8; j++) red[sgrp][d0 + j] = a[j];
    __syncthreads();

    if (tid < 128) {
        float s = 0.f;
        for (int g = 0; g < 16; g++) s += red[g][tid];
        atomicAdd(&accum[b * 128 + tid], s);
    }
}

// ---------------------------------------------------------------------------
// Kernel 5: out[b][c] = (accum[b][:]/2048) . Wl[:,c] + bl[c], fp32 out.
// 32 blocks spread the 4MB Wl read (R6 lesson: never 1 block).
// ---------------------------------------------------------------------------
__global__ void final_proj(const float* __restrict__ accum, const float* __restrict__ Wl,
                           const float* __restrict__ bl, float* __restrict__ out)
{
    int id = blockIdx.x * 256 + threadIdx.x;
    if (id >= NB * CC) return;
    int b = id / CC, c = id % CC;
    float s = 0.f;
    for (int d = 0; d < 128; d++)
        s += accum[b * 128 + d] * Wl[d * 1000 + c];
    out[id] = s * (1.0f / 2048.0f) + bl[c];
}

// ---------------------------------------------------------------------------
extern "C" void kernel_launch(void* const* d_in, const int* in_sizes, int n_in,
                              void* d_out, int out_size, void* d_ws, size_t ws_size,
                              hipStream_t stream) {
    const float* x  = (const float*)d_in[0];
    const float* Wq = (const float*)d_in[1];
    const float* bq = (const float*)d_in[2];
    const float* Wk = (const float*)d_in[3];
    const float* bk = (const float*)d_in[4];
    const float* Wv = (const float*)d_in[5];
    const float* bv = (const float*)d_in[6];
    const float* Wl = (const float*)d_in[7];
    const float* bl = (const float*)d_in[8];
    float* out = (float*)d_out;

    char* ws = (char*)d_ws;
    short* qo     = (short*)(ws);                 // 4 MiB
    short* ko     = (short*)(ws + 4194304);       // 4 MiB
    short* vo     = (short*)(ws + 8388608);       // 4 MiB, row-major [b][s][d]
    short* Wt     = (short*)(ws + 12582912);      // 384 KiB ([384][512] bf16)
    float* l_part = (float*)(ws + 12976128);      // 512 KiB (KC*8*2048 fp32)
    float* w_part = (float*)(ws + 13500416);      // 1 MiB (16*8*2048 fp32)
    float* acc    = (float*)(ws + 14548992);      // 4 KiB
    // total ~14 MiB of d_ws

    prep<<<768, 256, 0, stream>>>(Wq, Wk, Wv, Wt);
    qkv_mega<<<256, 512, 0, stream>>>(x, Wt, bq, bk, bv, qo, ko, vo);
    attn_l<<<dim3(16, 8, KC), 256, 0, stream>>>(qo, ko, l_part, acc);
    attn_w<<<dim3(16, 8, KC), 256, 0, stream>>>(qo, ko, l_part, w_part);
    wv<<<dim3(8, 16), 256, 0, stream>>>(w_part, vo, acc);
    final_proj<<<(NB * CC + 255) / 256, 256, 0, stream>>>(acc, Wl, bl, out);
}